// Round 12
// baseline (210.191 us; speedup 1.0000x reference)
//
#include <hip/hip_runtime.h>

// Problem constants (fixed by setup_inputs):
//   a_arc, s_arc : [64, 1024, 1024] f32
//   adds, pos    : [64, 1024] int32 in [0, 50)
constexpr int NPOS  = 50;
constexpr int NBINS = NPOS * NPOS;   // 2500
constexpr int SL    = 1024;
constexpr int BZ    = 64;
constexpr float ALPHA = 0.3f;

// ---------------- hist (register-acc row-gather) config ----------------
// Block = (batch b, p-range rg of size<=4, row-half). 13 ranges cover p=0..49.
constexpr int NRNG      = 13;
constexpr int SPLITS    = 2;                   // row-index halves (deterministic)
constexpr int PSLICE    = 208;                 // per-block slice stride (floats)
constexpr int H_THREADS = 256;                 // thread t owns cols 4t..4t+3
constexpr int H_BLOCKS  = BZ * NRNG * SPLITS;  // 1664

// ---------------- reduce2 / apply config ----------------
constexpr int R2_THREADS = 64;
constexpr int R2_BLOCKS  = (NBINS + R2_THREADS - 1) / R2_THREADS;  // 40
constexpr int A_THREADS      = 256;
constexpr int ROWS_PER_BLOCK = 32;
constexpr int BLOCKS_PER_B   = SL / ROWS_PER_BLOCK;   // 32
constexpr int A_BLOCKS       = BZ * BLOCKS_PER_B;     // 2048

// ---------------------------------------------------------------------------
// Kernel 1: per-(b, p-range, row-half) partials. Same verified machinery as
// R10 (counting-sorted row list, 1-KB/wave-instr full-row loads, 8-deep
// ping-pong, sentinel padding, q-sorted col-reduce) but the p-range is <=4 so
// the accumulator lives in 4 float4 REGISTERS (2-level block-uniform scalar
// branch tree) — no accL in the main loop. LDS drops 48->27 KB and the grid
// grows 512->1664: ~5 blocks/CU = 20 waves/CU vs R10's 8 (the one remaining
// structural difference from the 6.1-TB/s apply kernel).
// ---------------------------------------------------------------------------
__global__ __launch_bounds__(H_THREADS) void hist_gather(
    const float* __restrict__ a, const int* __restrict__ adds,
    float* __restrict__ g_part) {
  __shared__ int   adds_s[SL];          // 4 KB
  __shared__ float accL[4][SL];         // 16 KB (written once, after main loop)
  __shared__ int   list[512 + 8];       // 2 KB: (pl<<12)|row, this half only
  __shared__ int   order2[SL];          // 4 KB: cols sorted by q
  __shared__ int   cnt4[4], off4[4];
  __shared__ int   cntQ[NPOS], offQs[NPOS], offQm[NPOS];
  __shared__ int   nrows_s;

  const int tid  = threadIdx.x;
  const int b    = blockIdx.x / (NRNG * SPLITS);
  const int rem  = blockIdx.x % (NRNG * SPLITS);
  const int rg   = rem >> 1;
  const int half = rem & 1;
  const int lo   = rg * 4;
  const int sz   = (lo + 4 <= NPOS) ? 4 : (NPOS - lo);   // 4, last range 2
  const int r0   = half * (SL / SPLITS);

  ((int4*)adds_s)[tid] = ((const int4*)(adds + (size_t)b * SL))[tid];
  if (tid < 4) cnt4[tid] = 0;
  if (tid < NPOS) cntQ[tid] = 0;
  __syncthreads();

  // --- counts: this half's rows by pl; ALL cols by q (verified pattern) ---
  for (int i = tid; i < SL; i += H_THREADS) atomicAdd(&cntQ[adds_s[i]], 1);
  for (int i = r0 + tid; i < r0 + SL / SPLITS; i += H_THREADS) {
    const int pl = adds_s[i] - lo;
    if ((unsigned)pl < (unsigned)sz) atomicAdd(&cnt4[pl], 1);
  }
  __syncthreads();
  if (tid == 0) {                       // wave 0: row prefix
    int run = 0;
    #pragma unroll
    for (int c = 0; c < 4; ++c) { off4[c] = run; run += cnt4[c]; }
    nrows_s = run;
  } else if (tid == 64) {               // wave 1: col prefix, concurrent
    int run = 0;
    for (int c = 0; c < NPOS; ++c) { offQs[c] = run; offQm[c] = run; run += cntQ[c]; }
  }
  __syncthreads();
  for (int i = r0 + tid; i < r0 + SL / SPLITS; i += H_THREADS) {
    const int pl = adds_s[i] - lo;
    if ((unsigned)pl < (unsigned)sz)
      list[atomicAdd(&off4[pl], 1)] = (pl << 12) | i;
  }
  for (int i = tid; i < SL; i += H_THREADS)
    order2[atomicAdd(&offQm[adds_s[i]], 1)] = i;
  __syncthreads();
  const int N    = nrows_s;
  const int Npad = (N + 7) & ~7;
  if (tid < 8 && N + tid < Npad)        // sentinel pl=7 -> dummy acc
    list[N + tid] = (7 << 12) | (N > 0 ? (list[N - 1] & 0xFFF) : 0);
  __syncthreads();

  // --- main loop: gathered full-row stream, register accumulation ---
  const float4* __restrict__ Ab = (const float4*)(a + (size_t)b * SL * SL);
  float4 a0{0,0,0,0}, a1{0,0,0,0}, a2{0,0,0,0}, a3{0,0,0,0}, ad{0,0,0,0};

  auto addto = [&](int pl, const float4& v) {   // pl is block-uniform (SGPR)
    if (pl < 2) {
      if (pl == 0) { a0.x += v.x; a0.y += v.y; a0.z += v.z; a0.w += v.w; }
      else         { a1.x += v.x; a1.y += v.y; a1.z += v.z; a1.w += v.w; }
    } else if (pl < 4) {
      if (pl == 2) { a2.x += v.x; a2.y += v.y; a2.z += v.z; a2.w += v.w; }
      else         { a3.x += v.x; a3.y += v.y; a3.z += v.z; a3.w += v.w; }
    } else         { ad.x += v.x; ad.y += v.y; ad.z += v.z; ad.w += v.w; }
  };

  int    eA[8], eB[8];
  float4 vA[8], vB[8];
  auto loadbank = [&](int (&e)[8], float4 (&v)[8], int k) {
    #pragma unroll
    for (int u = 0; u < 8; ++u) {
      e[u] = __builtin_amdgcn_readfirstlane(list[k + u]);  // uniform -> SGPR
      v[u] = Ab[(size_t)(e[u] & 0xFFF) * (SL / 4) + tid];  // 1 KB/wave-instr
    }
  };
  auto procbank = [&](int (&e)[8], float4 (&v)[8]) {
    #pragma unroll
    for (int u = 0; u < 8; ++u) addto(e[u] >> 12, v[u]);
  };

  if (Npad > 0) {
    loadbank(eA, vA, 0);
    for (int k = 0; k < Npad; k += 16) {
      if (k + 8 < Npad) loadbank(eB, vB, k + 8);
      procbank(eA, vA);
      if (k + 16 < Npad) loadbank(eA, vA, k + 16);
      if (k + 8 < Npad) procbank(eB, vB);
    }
  }

  // --- dump registers to accL, then q-sorted col-reduce (verified) ---
  ((float4*)&accL[0][0])[tid] = a0;
  ((float4*)&accL[1][0])[tid] = a1;
  ((float4*)&accL[2][0])[tid] = a2;
  ((float4*)&accL[3][0])[tid] = a3;
  __syncthreads();

  float* __restrict__ gp = g_part + (size_t)blockIdx.x * PSLICE;
  for (int bin = tid; bin < sz * NPOS; bin += H_THREADS) {
    const int pl = bin / NPOS, q = bin % NPOS;
    const int s0 = offQs[q], n = cntQ[q];
    float s = 0.0f;
    for (int k2 = 0; k2 < n; ++k2) s += accL[pl][order2[s0 + k2]];
    gp[bin] = s;                        // plain store, private slice
  }
}

// ---------------------------------------------------------------------------
// Kernel 1.5: g_hist[bin] = sum over 64 batches x 2 halves. Plain stores,
// one thread per bin -> no atomics, no memset anywhere.
// ---------------------------------------------------------------------------
__global__ __launch_bounds__(R2_THREADS) void reduce2(
    const float* __restrict__ g_part, float* __restrict__ g_hist) {
  const int bin = blockIdx.x * R2_THREADS + threadIdx.x;
  if (bin >= NBINS) return;
  const int p = bin / NPOS, q = bin % NPOS;
  const int rg = p >> 2, pl = p & 3;
  const float* __restrict__ base =
      g_part + (size_t)(rg * SPLITS) * PSLICE + pl * NPOS + q;
  float s = 0.0f;
  #pragma unroll 4
  for (int bb = 0; bb < BZ; ++bb) {
    const size_t o = (size_t)bb * (NRNG * SPLITS) * PSLICE;
    s += base[o] + base[o + PSLICE];
  }
  g_hist[bin] = s;
}

// ---------------------------------------------------------------------------
// Kernel 2: out = s_arc + ALPHA * sigmoid(g_hist)[pos-pair bin]
// Measured ~6.1 TB/s (HBM roofline) — unchanged.
// ---------------------------------------------------------------------------
__global__ __launch_bounds__(A_THREADS) void apply_kernel(
    const float* __restrict__ s, const int* __restrict__ pos,
    const float* __restrict__ g_hist, float* __restrict__ out) {
  __shared__ float sig[NBINS];
  __shared__ int   pos_s[SL];

  const int tid = threadIdx.x;
  const int b   = blockIdx.x / BLOCKS_PER_B;
  const int i0  = (blockIdx.x % BLOCKS_PER_B) * ROWS_PER_BLOCK;

  ((int4*)pos_s)[tid] = ((const int4*)(pos + (size_t)b * SL))[tid];
  for (int k = tid; k < NBINS; k += A_THREADS) {
    const float h = g_hist[k];
    sig[k] = 1.0f / (1.0f + __expf(-h));
  }
  __syncthreads();

  const int4 pj = ((const int4*)pos_s)[tid];
  const size_t rowoff = ((size_t)b * SL + i0) * SL;
  const float4* __restrict__ srow = (const float4*)(s + rowoff);
  float4* __restrict__ orow = (float4*)(out + rowoff);

  for (int r = 0; r < ROWS_PER_BLOCK; ++r) {
    const int base = pos_s[i0 + r] * NPOS;    // wave-uniform broadcast
    const float4 sv = srow[(size_t)r * (SL / 4) + tid];
    float4 ov;
    ov.x = sv.x + ALPHA * sig[base + pj.x];
    ov.y = sv.y + ALPHA * sig[base + pj.y];
    ov.z = sv.z + ALPHA * sig[base + pj.z];
    ov.w = sv.w + ALPHA * sig[base + pj.w];
    orow[(size_t)r * (SL / 4) + tid] = ov;
  }
}

extern "C" void kernel_launch(void* const* d_in, const int* in_sizes, int n_in,
                              void* d_out, int out_size, void* d_ws, size_t ws_size,
                              hipStream_t stream) {
  const float* a_arc = (const float*)d_in[0];
  const float* s_arc = (const float*)d_in[1];
  const int*   adds  = (const int*)d_in[2];
  const int*   pos   = (const int*)d_in[3];
  float* out    = (float*)d_out;
  float* g_hist = (float*)d_ws;                 // 2500 floats
  float* g_part = g_hist + 4096;                // 1664 x 208 floats = 1.4 MB

  // No memset needed: g_part slices and g_hist are fully overwritten with
  // plain stores every call (no atomic accumulation anywhere).
  hist_gather <<<H_BLOCKS, H_THREADS, 0, stream>>>(a_arc, adds, g_part);
  reduce2     <<<R2_BLOCKS, R2_THREADS, 0, stream>>>(g_part, g_hist);
  apply_kernel<<<A_BLOCKS, A_THREADS, 0, stream>>>(s_arc, pos, g_hist, out);
}